// Round 1
// baseline (1417.642 us; speedup 1.0000x reference)
//
#include <hip/hip_runtime.h>
#include <hip/hip_bf16.h>
#include <cfloat>

// VecPointNet on MI355X, round 1: correct fp32 implementation.
// Pipeline: prep (transpose+sqnorm) -> knn (top-16 lexicographic) ->
// edge features + input LNA -> 4x [GEMM-LNA(Wl), mean_N, bias, GEMM-LNA(Wg)+partial W_out GEMM]
// -> mean_N for output 0.

// ---------------- prep: pts4[b][n] = (x,y,z, x^2+y^2+z^2) ----------------
__global__ __launch_bounds__(256) void prep_kernel(const float* __restrict__ x,
                                                   float4* __restrict__ pts4,
                                                   int N, int B) {
    int t = blockIdx.x * 256 + threadIdx.x;
    if (t >= B * N) return;
    int b = t / N, n = t - b * N;
    const float* xb = x + (long)b * 3 * N;
    float px = xb[n], py = xb[N + n], pz = xb[2 * N + n];
    float sq = px * px + py * py + pz * pz;
    pts4[t] = make_float4(px, py, pz, sq);
}

// ---------------- knn: per query, 16 smallest (d2, idx) lexicographic ----------------
// grid = B*(N/32), block 256. 8 sub-threads per query, each scans m === sub (mod 8).
// Lexicographic key (d2, idx) == jax.lax.top_k tie-breaking (earlier index wins).
__global__ __launch_bounds__(256) void knn_kernel(const float4* __restrict__ pts4,
                                                  int* __restrict__ idxOut, int N) {
    __shared__ float4 cbuf[512];
    __shared__ float mbd[256 * 17];
    __shared__ int   mbi[256 * 17];
    int t = threadIdx.x;
    int tilesPerB = N / 32;
    int b = blockIdx.x / tilesPerB;
    int q0 = (blockIdx.x % tilesPerB) * 32;
    int qi = t & 31, sub = t >> 5;
    float4 Q = pts4[b * N + q0 + qi];
    int base = t * 17;
#pragma unroll
    for (int s = 0; s < 16; ++s) { mbd[base + s] = FLT_MAX; mbi[base + s] = 0x7fffffff; }
    float maxv = FLT_MAX; int maxi = 0x7fffffff; int maxpos = 0;

    for (int c0 = 0; c0 < N; c0 += 512) {
        __syncthreads();
        cbuf[t]       = pts4[b * N + c0 + t];
        cbuf[t + 256] = pts4[b * N + c0 + t + 256];
        __syncthreads();
        for (int j = sub; j < 512; j += 8) {
            float4 C = cbuf[j];
            float dot = Q.x * C.x + Q.y * C.y + Q.z * C.z;
            float d2 = Q.w + C.w - 2.0f * dot;   // same formula as reference
            int m = c0 + j;
            if (d2 < maxv || (d2 == maxv && m < maxi)) {
                mbd[base + maxpos] = d2; mbi[base + maxpos] = m;
                maxv = mbd[base]; maxi = mbi[base]; maxpos = 0;
#pragma unroll
                for (int s = 1; s < 16; ++s) {
                    float dv = mbd[base + s]; int iv = mbi[base + s];
                    if (dv > maxv || (dv == maxv && iv > maxi)) { maxv = dv; maxi = iv; maxpos = s; }
                }
            }
        }
    }
    __syncthreads();
    if (t < 32) {  // merge the 8 partial lists of query (q0+t)
        int abase = t * 17;
        float mv = mbd[abase]; int mi = mbi[abase]; int mp = 0;
#pragma unroll
        for (int s = 1; s < 16; ++s) {
            float dv = mbd[abase + s]; int iv = mbi[abase + s];
            if (dv > mv || (dv == mv && iv > mi)) { mv = dv; mi = iv; mp = s; }
        }
        for (int src = 1; src < 8; ++src) {
            int sb = (src * 32 + t) * 17;
            for (int s = 0; s < 16; ++s) {
                float dv = mbd[sb + s]; int iv = mbi[sb + s];
                if (dv < mv || (dv == mv && iv < mi)) {
                    mbd[abase + mp] = dv; mbi[abase + mp] = iv;
                    mv = mbd[abase]; mi = mbi[abase]; mp = 0;
#pragma unroll
                    for (int s2 = 1; s2 < 16; ++s2) {
                        float d2v = mbd[abase + s2]; int i2v = mbi[abase + s2];
                        if (d2v > mv || (d2v == mv && i2v > mi)) { mv = d2v; mi = i2v; mp = s2; }
                    }
                }
            }
        }
        int q = q0 + t;
        for (int s = 0; s < 16; ++s) idxOut[(b * N + q) * 16 + s] = mbi[abase + s];
    }
}

// ---------------- edge features + input LNA + mean over K ----------------
// grid = B*(N/8), block 256: o = t&127, h = t>>7 handles 4 points each.
__global__ __launch_bounds__(256) void edge_kernel(const float4* __restrict__ pts4,
                                                   const int* __restrict__ idx,
                                                   const float* __restrict__ Win,
                                                   const float* __restrict__ Uin,
                                                   float* __restrict__ h0, int N) {
    __shared__ float4 nbuf[8][16];
    __shared__ float4 cpt[8];
    int nTiles = N / 8;
    int b = blockIdx.x / nTiles;
    int n0 = (blockIdx.x % nTiles) * 8;
    int t = threadIdx.x;
    if (t < 128) {
        int pl = t >> 4, k = t & 15;
        int nb = idx[(b * N + n0 + pl) * 16 + k];
        nbuf[pl][k] = pts4[b * N + nb];
    } else if (t < 136) {
        cpt[t - 128] = pts4[b * N + n0 + (t - 128)];
    }
    __syncthreads();
    int o = t & 127, h = t >> 7;
    float w0 = Win[o * 3], w1 = Win[o * 3 + 1], w2 = Win[o * 3 + 2];
    float u0 = Uin[o * 3], u1 = Uin[o * 3 + 1], u2 = Uin[o * 3 + 2];
    for (int pl = h * 4; pl < h * 4 + 4; ++pl) {
        float4 c4 = cpt[pl];
        float inv = 1.0f / fmaxf(sqrtf(c4.w), 1e-12f);
        float ax = c4.x * inv, ay = c4.y * inv, az = c4.z * inv;
        float a0 = 0.f, a1 = 0.f, a2 = 0.f;
        for (int k = 0; k < 16; ++k) {
            float4 nb = nbuf[pl][k];
            float cr0 = ay * nb.z - az * nb.y;
            float cr1 = az * nb.x - ax * nb.z;
            float cr2 = ax * nb.y - ay * nb.x;
            float df0 = nb.x - c4.x, df1 = nb.y - c4.y, df2 = nb.z - c4.z;
            float P0 = w0 * cr0 + w1 * df0 + w2 * c4.x;
            float P1 = w0 * cr1 + w1 * df1 + w2 * c4.y;
            float P2 = w0 * cr2 + w1 * df2 + w2 * c4.z;
            float D0 = u0 * cr0 + u1 * df0 + u2 * c4.x;
            float D1 = u0 * cr1 + u1 * df1 + u2 * c4.y;
            float D2 = u0 * cr2 + u1 * df2 + u2 * c4.z;
            float dot = P0 * D0 + P1 * D1 + P2 * D2;
            float dsq = D0 * D0 + D1 * D1 + D2 * D2;
            if (dot < 0.0f) {
                float s = dot / (dsq + 1e-6f);
                P0 -= s * D0; P1 -= s * D1; P2 -= s * D2;
            }
            a0 += P0; a1 += P1; a2 += P2;
        }
        long basei = (long)b * 128 * 3 * N + (long)(o * 3) * N + n0 + pl;
        h0[basei]         = a0 * (1.0f / 16.0f);
        h0[basei + N]     = a1 * (1.0f / 16.0f);
        h0[basei + 2 * N] = a2 * (1.0f / 16.0f);
    }
}

// ---------------- GEMM (+optional LNA, +optional bias, +optional accumulate) ----------------
// Yin: (B, K, 3, N) with batch stride yBS. W,U rows of length ldw (cols [0,K) used).
// Out: (B, 128, 3, N) with batch stride oBS.
// block 256: opair = t&63 -> o, o+64 ; q = t>>6 -> points q*4..q*4+3 of a 16-pt tile.
template<bool LNA>
__global__ __launch_bounds__(256) void gemm_lna_kernel(
    const float* __restrict__ Yin, long yBS,
    const float* __restrict__ W, const float* __restrict__ U, int ldw,
    const float* __restrict__ biasP, const float* __restrict__ biasD, int hasBias,
    float* __restrict__ Out, long oBS, int K, int N, int accum)
{
    __shared__ float Wt[32][129];
    __shared__ float Ut[LNA ? 32 : 1][129];
    __shared__ float4 Ysh[32][16];
    int t = threadIdx.x;
    int nTiles = N / 16;
    int b = blockIdx.x / nTiles;
    int n0 = (blockIdx.x % nTiles) * 16;
    int op = t & 63, q = t >> 6;
    float pA[2][4][3] = {};
    float dA[2][4][3] = {};

    int nCh = K / 32;
    for (int kc = 0; kc < nCh; ++kc) {
        int i0 = kc * 32;
        __syncthreads();
        for (int e = t; e < 4096; e += 256) {
            int i = e & 31, o = e >> 5;
            Wt[i][o] = W[(long)o * ldw + i0 + i];
            if (LNA) Ut[i][o] = U[(long)o * ldw + i0 + i];
        }
        for (int e = t; e < 1536; e += 256) {
            int pt = e & 15; int r = e >> 4; int c = r % 3; int i = r / 3;
            ((float*)&Ysh[i][pt])[c] =
                Yin[(long)b * yBS + (long)((i0 + i) * 3 + c) * N + n0 + pt];
        }
        __syncthreads();
#pragma unroll 8
        for (int i = 0; i < 32; ++i) {
            float w0 = Wt[i][op], w1 = Wt[i][op + 64];
            float u0 = 0.f, u1 = 0.f;
            if (LNA) { u0 = Ut[i][op]; u1 = Ut[i][op + 64]; }
#pragma unroll
            for (int p = 0; p < 4; ++p) {
                float4 y = Ysh[i][(q << 2) + p];
                pA[0][p][0] = fmaf(w0, y.x, pA[0][p][0]);
                pA[0][p][1] = fmaf(w0, y.y, pA[0][p][1]);
                pA[0][p][2] = fmaf(w0, y.z, pA[0][p][2]);
                pA[1][p][0] = fmaf(w1, y.x, pA[1][p][0]);
                pA[1][p][1] = fmaf(w1, y.y, pA[1][p][1]);
                pA[1][p][2] = fmaf(w1, y.z, pA[1][p][2]);
                if (LNA) {
                    dA[0][p][0] = fmaf(u0, y.x, dA[0][p][0]);
                    dA[0][p][1] = fmaf(u0, y.y, dA[0][p][1]);
                    dA[0][p][2] = fmaf(u0, y.z, dA[0][p][2]);
                    dA[1][p][0] = fmaf(u1, y.x, dA[1][p][0]);
                    dA[1][p][1] = fmaf(u1, y.y, dA[1][p][1]);
                    dA[1][p][2] = fmaf(u1, y.z, dA[1][p][2]);
                }
            }
        }
    }
#pragma unroll
    for (int j = 0; j < 2; ++j) {
        int o = op + j * 64;
        float bp0 = 0.f, bp1 = 0.f, bp2 = 0.f, bq0 = 0.f, bq1 = 0.f, bq2 = 0.f;
        if (hasBias) {
            long bb = ((long)b * 128 + o) * 3;
            bp0 = biasP[bb]; bp1 = biasP[bb + 1]; bp2 = biasP[bb + 2];
            if (LNA) { bq0 = biasD[bb]; bq1 = biasD[bb + 1]; bq2 = biasD[bb + 2]; }
        }
        float res[3][4];
#pragma unroll
        for (int p = 0; p < 4; ++p) {
            float P0 = pA[j][p][0] + bp0, P1 = pA[j][p][1] + bp1, P2 = pA[j][p][2] + bp2;
            if (LNA) {
                float D0 = dA[j][p][0] + bq0, D1 = dA[j][p][1] + bq1, D2 = dA[j][p][2] + bq2;
                float dot = P0 * D0 + P1 * D1 + P2 * D2;
                float dsq = D0 * D0 + D1 * D1 + D2 * D2;
                if (dot < 0.0f) {
                    float s = dot / (dsq + 1e-6f);
                    P0 -= s * D0; P1 -= s * D1; P2 -= s * D2;
                }
            }
            res[0][p] = P0; res[1][p] = P1; res[2][p] = P2;
        }
        long ob = (long)b * oBS + (long)(o * 3) * N + n0 + (q << 2);
#pragma unroll
        for (int c = 0; c < 3; ++c) {
            float4 v = make_float4(res[c][0], res[c][1], res[c][2], res[c][3]);
            float4* dst = (float4*)(Out + ob + (long)c * N);
            if (accum) {
                float4 old = *dst;
                v.x += old.x; v.y += old.y; v.z += old.z; v.w += old.w;
            }
            *dst = v;
        }
    }
}

// ---------------- mean over N per (b, channel, comp) row ----------------
__global__ __launch_bounds__(256) void reduce_mean_kernel(const float* __restrict__ src, long bs,
                                                          float* __restrict__ dst, int N) {
    __shared__ float red[256];
    int row = blockIdx.x;          // row = (b*128+o)*3 + c, 0..767
    int b = row / 384; int rr = row % 384;
    const float* p = src + (long)b * bs + (long)rr * N;
    float s = 0.f;
    for (int i = threadIdx.x; i < N; i += 256) s += p[i];
    red[threadIdx.x] = s;
    __syncthreads();
    for (int st = 128; st > 0; st >>= 1) {
        if (threadIdx.x < st) red[threadIdx.x] += red[threadIdx.x + st];
        __syncthreads();
    }
    if (threadIdx.x == 0) dst[row] = red[0] / (float)N;
}

// ---------------- bias from global-mean half of Wg/Ug ----------------
// biasP[(b*128+o)*3+c] = sum_i Wg[o*256+128+i] * yg[(b*128+i)*3+c]
__global__ __launch_bounds__(256) void bias_kernel(const float* __restrict__ Wg,
                                                   const float* __restrict__ Ug,
                                                   const float* __restrict__ yg,
                                                   float* __restrict__ biasP,
                                                   float* __restrict__ biasD) {
    int t = blockIdx.x * 256 + threadIdx.x;
    if (t >= 768) return;
    int c = t % 3; int o = (t / 3) % 128; int b = t / 384;
    float sp = 0.f, sd = 0.f;
    for (int i = 0; i < 128; ++i) {
        float y = yg[((long)b * 128 + i) * 3 + c];
        sp = fmaf(Wg[o * 256 + 128 + i], y, sp);
        sd = fmaf(Ug[o * 256 + 128 + i], y, sd);
    }
    biasP[t] = sp;
    biasD[t] = sd;
}

extern "C" void kernel_launch(void* const* d_in, const int* in_sizes, int n_in,
                              void* d_out, int out_size, void* d_ws, size_t ws_size,
                              hipStream_t stream) {
    const float* x    = (const float*)d_in[0];
    const float* Win  = (const float*)d_in[1];
    const float* Uin  = (const float*)d_in[2];
    const float* Wl   = (const float*)d_in[3];
    const float* Ul   = (const float*)d_in[4];
    const float* Wg   = (const float*)d_in[5];
    const float* Ug   = (const float*)d_in[6];
    const float* Wout = (const float*)d_in[7];

    const int B = 2, N = 4096, H = 128;
    float* out0 = (float*)d_out;                 // (B,128,3) mean
    float* out1 = out0 + (long)B * H * 3;        // (B,128,3,N)

    float* ws = (float*)d_ws;
    long off = 0;
    float4* pts4 = (float4*)ws;                  off += (long)B * N * 4;
    int* idx = (int*)(ws + off);                 off += (long)B * N * 16;
    float* bufA = ws + off;                      off += (long)B * H * 3 * N;
    float* bufB = ws + off;                      off += (long)B * H * 3 * N;
    float* yg    = ws + off;                     off += B * H * 3;
    float* biasP = ws + off;                     off += B * H * 3;
    float* biasD = ws + off;                     off += B * H * 3;
    // total ~25.8 MB of workspace

    long bs128 = (long)H * 3 * N;

    prep_kernel<<<(B * N + 255) / 256, 256, 0, stream>>>(x, pts4, N, B);
    knn_kernel<<<B * (N / 32), 256, 0, stream>>>(pts4, idx, N);
    edge_kernel<<<B * (N / 8), 256, 0, stream>>>(pts4, idx, Win, Uin, bufA, N);

    for (int l = 0; l < 4; ++l) {
        // y1 = LNA(Wl y, Ul y)
        gemm_lna_kernel<true><<<B * (N / 16), 256, 0, stream>>>(
            bufA, bs128, Wl + l * H * H, Ul + l * H * H, H,
            nullptr, nullptr, 0, bufB, bs128, H, N, 0);
        // yg = mean_N(y1); bias = Wg[:,128:] @ yg (and Ug)
        reduce_mean_kernel<<<B * H * 3, 256, 0, stream>>>(bufB, bs128, yg, N);
        bias_kernel<<<3, 256, 0, stream>>>(Wg + l * H * 256, Ug + l * H * 256, yg, biasP, biasD);
        // y2 = LNA(Wg[:, :128] y1 + biasP, Ug[:, :128] y1 + biasD)
        gemm_lna_kernel<true><<<B * (N / 16), 256, 0, stream>>>(
            bufB, bs128, Wg + l * H * 256, Ug + l * H * 256, 256,
            biasP, biasD, 1, bufA, bs128, H, N, 0);
        // out1 (+)= W_out[:, l*128:(l+1)*128] @ y2
        gemm_lna_kernel<false><<<B * (N / 16), 256, 0, stream>>>(
            bufA, bs128, Wout + l * H, nullptr, 4 * H,
            nullptr, nullptr, 0, out1, bs128, H, N, l > 0 ? 1 : 0);
    }
    reduce_mean_kernel<<<B * H * 3, 256, 0, stream>>>(out1, bs128, out0, N);
}

// Round 2
// 689.885 us; speedup vs baseline: 2.0549x; 2.0549x over previous
//
#include <hip/hip_runtime.h>
#include <hip/hip_bf16.h>
#include <cfloat>

// VecPointNet on MI355X, round 2: wave-cooperative kNN (ballot + distributed
// sorted top-16). Rest of pipeline unchanged from round 1 (passed, absmax 0.004).

// ---------------- prep: pts4[b][n] = (x,y,z, x^2+y^2+z^2) ----------------
__global__ __launch_bounds__(256) void prep_kernel(const float* __restrict__ x,
                                                   float4* __restrict__ pts4,
                                                   int N, int B) {
    int t = blockIdx.x * 256 + threadIdx.x;
    if (t >= B * N) return;
    int b = t / N, n = t - b * N;
    const float* xb = x + (long)b * 3 * N;
    float px = xb[n], py = xb[N + n], pz = xb[2 * N + n];
    float sq = px * px + py * py + pz * pz;
    pts4[t] = make_float4(px, py, pz, sq);
}

// ---------------- knn: one wave per query, ballot-filtered top-16 ----------------
// block = 1024 (16 waves = 16 queries), grid = B*(N/16) = 512 blocks.
// LDS: full batch of 4096 float4 points (64 KB) -> 2 blocks/CU, 100% occupancy.
// Key = (double)orderable_u32(d2) * 4096 + candidate_index: ascending double
// order == lexicographic (d2, idx) == jax.lax.top_k tie semantics.
// Sorted top-16 lives distributed across lanes 0..15 (ascending); T = lane15's
// key broadcast. Per 64-candidate chunk: 1 ds_read_b128 + ~12 VALU + 1 ballot;
// insertions (expected ~90/query total) serialize via ffs + shfl + shfl_up shift.
__global__ __launch_bounds__(1024) void knn_kernel(const float4* __restrict__ pts4,
                                                   int* __restrict__ idxOut, int N) {
    __shared__ float4 cbuf[4096];   // 64 KB
    int t = threadIdx.x;
    int tilesPerB = N / 16;
    int b = blockIdx.x / tilesPerB;
    int q = (blockIdx.x % tilesPerB) * 16 + (t >> 6);
    int lane = t & 63;

    for (int i = t; i < N; i += 1024) cbuf[i] = pts4[b * N + i];
    __syncthreads();

    float4 Q = cbuf[q];
    double k = 1e300;     // lanes 0..15: sorted ascending top-16 keys
    double T = 1e300;     // current 16th-best key (uniform)

    for (int c0 = 0; c0 < N; c0 += 64) {
        float4 C = cbuf[c0 + lane];
        float dot = Q.x * C.x + Q.y * C.y + Q.z * C.z;
        float d2 = Q.w + C.w - 2.0f * dot;          // same formula as reference
        unsigned u = __float_as_uint(d2);
        u ^= (unsigned)((int)u >> 31) | 0x80000000u; // orderable uint
        double key = (double)u * 4096.0 + (double)(c0 + lane);
        unsigned long long mask = __ballot(key < T);
        while (mask) {
            int src = __ffsll(mask) - 1;
            mask &= mask - 1;
            double vb = __shfl(key, src);
            if (vb < T) {                            // uniform branch (stale-mask recheck)
                double km1 = __shfl_up(k, 1);
                if (lane == 0) km1 = -1.0;
                // sorted insert: k'[l] = (k[l] <= vb) ? k[l] : max(vb, k[l-1])
                double kn = (vb <= km1) ? km1 : ((vb < k) ? vb : k);
                if (lane < 16) k = kn;
                T = __shfl(k, 15);
            }
        }
    }
    if (lane < 16) {
        long long kl = (long long)k;                 // exact (key < 2^44)
        idxOut[(b * N + q) * 16 + lane] = (int)(kl & 4095);
    }
}

// ---------------- edge features + input LNA + mean over K ----------------
// grid = B*(N/8), block 256: o = t&127, h = t>>7 handles 4 points each.
__global__ __launch_bounds__(256) void edge_kernel(const float4* __restrict__ pts4,
                                                   const int* __restrict__ idx,
                                                   const float* __restrict__ Win,
                                                   const float* __restrict__ Uin,
                                                   float* __restrict__ h0, int N) {
    __shared__ float4 nbuf[8][16];
    __shared__ float4 cpt[8];
    int nTiles = N / 8;
    int b = blockIdx.x / nTiles;
    int n0 = (blockIdx.x % nTiles) * 8;
    int t = threadIdx.x;
    if (t < 128) {
        int pl = t >> 4, k = t & 15;
        int nb = idx[(b * N + n0 + pl) * 16 + k];
        nbuf[pl][k] = pts4[b * N + nb];
    } else if (t < 136) {
        cpt[t - 128] = pts4[b * N + n0 + (t - 128)];
    }
    __syncthreads();
    int o = t & 127, h = t >> 7;
    float w0 = Win[o * 3], w1 = Win[o * 3 + 1], w2 = Win[o * 3 + 2];
    float u0 = Uin[o * 3], u1 = Uin[o * 3 + 1], u2 = Uin[o * 3 + 2];
    for (int pl = h * 4; pl < h * 4 + 4; ++pl) {
        float4 c4 = cpt[pl];
        float inv = 1.0f / fmaxf(sqrtf(c4.w), 1e-12f);
        float ax = c4.x * inv, ay = c4.y * inv, az = c4.z * inv;
        float a0 = 0.f, a1 = 0.f, a2 = 0.f;
        for (int k = 0; k < 16; ++k) {
            float4 nb = nbuf[pl][k];
            float cr0 = ay * nb.z - az * nb.y;
            float cr1 = az * nb.x - ax * nb.z;
            float cr2 = ax * nb.y - ay * nb.x;
            float df0 = nb.x - c4.x, df1 = nb.y - c4.y, df2 = nb.z - c4.z;
            float P0 = w0 * cr0 + w1 * df0 + w2 * c4.x;
            float P1 = w0 * cr1 + w1 * df1 + w2 * c4.y;
            float P2 = w0 * cr2 + w1 * df2 + w2 * c4.z;
            float D0 = u0 * cr0 + u1 * df0 + u2 * c4.x;
            float D1 = u0 * cr1 + u1 * df1 + u2 * c4.y;
            float D2 = u0 * cr2 + u1 * df2 + u2 * c4.z;
            float dot = P0 * D0 + P1 * D1 + P2 * D2;
            float dsq = D0 * D0 + D1 * D1 + D2 * D2;
            if (dot < 0.0f) {
                float s = dot / (dsq + 1e-6f);
                P0 -= s * D0; P1 -= s * D1; P2 -= s * D2;
            }
            a0 += P0; a1 += P1; a2 += P2;
        }
        long basei = (long)b * 128 * 3 * N + (long)(o * 3) * N + n0 + pl;
        h0[basei]         = a0 * (1.0f / 16.0f);
        h0[basei + N]     = a1 * (1.0f / 16.0f);
        h0[basei + 2 * N] = a2 * (1.0f / 16.0f);
    }
}

// ---------------- GEMM (+optional LNA, +optional bias, +optional accumulate) ----------------
// Yin: (B, K, 3, N) with batch stride yBS. W,U rows of length ldw (cols [0,K) used).
// Out: (B, 128, 3, N) with batch stride oBS.
// block 256: opair = t&63 -> o, o+64 ; q = t>>6 -> points q*4..q*4+3 of a 16-pt tile.
template<bool LNA>
__global__ __launch_bounds__(256) void gemm_lna_kernel(
    const float* __restrict__ Yin, long yBS,
    const float* __restrict__ W, const float* __restrict__ U, int ldw,
    const float* __restrict__ biasP, const float* __restrict__ biasD, int hasBias,
    float* __restrict__ Out, long oBS, int K, int N, int accum)
{
    __shared__ float Wt[32][129];
    __shared__ float Ut[LNA ? 32 : 1][129];
    __shared__ float4 Ysh[32][16];
    int t = threadIdx.x;
    int nTiles = N / 16;
    int b = blockIdx.x / nTiles;
    int n0 = (blockIdx.x % nTiles) * 16;
    int op = t & 63, q = t >> 6;
    float pA[2][4][3] = {};
    float dA[2][4][3] = {};

    int nCh = K / 32;
    for (int kc = 0; kc < nCh; ++kc) {
        int i0 = kc * 32;
        __syncthreads();
        for (int e = t; e < 4096; e += 256) {
            int i = e & 31, o = e >> 5;
            Wt[i][o] = W[(long)o * ldw + i0 + i];
            if (LNA) Ut[i][o] = U[(long)o * ldw + i0 + i];
        }
        for (int e = t; e < 1536; e += 256) {
            int pt = e & 15; int r = e >> 4; int c = r % 3; int i = r / 3;
            ((float*)&Ysh[i][pt])[c] =
                Yin[(long)b * yBS + (long)((i0 + i) * 3 + c) * N + n0 + pt];
        }
        __syncthreads();
#pragma unroll 8
        for (int i = 0; i < 32; ++i) {
            float w0 = Wt[i][op], w1 = Wt[i][op + 64];
            float u0 = 0.f, u1 = 0.f;
            if (LNA) { u0 = Ut[i][op]; u1 = Ut[i][op + 64]; }
#pragma unroll
            for (int p = 0; p < 4; ++p) {
                float4 y = Ysh[i][(q << 2) + p];
                pA[0][p][0] = fmaf(w0, y.x, pA[0][p][0]);
                pA[0][p][1] = fmaf(w0, y.y, pA[0][p][1]);
                pA[0][p][2] = fmaf(w0, y.z, pA[0][p][2]);
                pA[1][p][0] = fmaf(w1, y.x, pA[1][p][0]);
                pA[1][p][1] = fmaf(w1, y.y, pA[1][p][1]);
                pA[1][p][2] = fmaf(w1, y.z, pA[1][p][2]);
                if (LNA) {
                    dA[0][p][0] = fmaf(u0, y.x, dA[0][p][0]);
                    dA[0][p][1] = fmaf(u0, y.y, dA[0][p][1]);
                    dA[0][p][2] = fmaf(u0, y.z, dA[0][p][2]);
                    dA[1][p][0] = fmaf(u1, y.x, dA[1][p][0]);
                    dA[1][p][1] = fmaf(u1, y.y, dA[1][p][1]);
                    dA[1][p][2] = fmaf(u1, y.z, dA[1][p][2]);
                }
            }
        }
    }
#pragma unroll
    for (int j = 0; j < 2; ++j) {
        int o = op + j * 64;
        float bp0 = 0.f, bp1 = 0.f, bp2 = 0.f, bq0 = 0.f, bq1 = 0.f, bq2 = 0.f;
        if (hasBias) {
            long bb = ((long)b * 128 + o) * 3;
            bp0 = biasP[bb]; bp1 = biasP[bb + 1]; bp2 = biasP[bb + 2];
            if (LNA) { bq0 = biasD[bb]; bq1 = biasD[bb + 1]; bq2 = biasD[bb + 2]; }
        }
        float res[3][4];
#pragma unroll
        for (int p = 0; p < 4; ++p) {
            float P0 = pA[j][p][0] + bp0, P1 = pA[j][p][1] + bp1, P2 = pA[j][p][2] + bp2;
            if (LNA) {
                float D0 = dA[j][p][0] + bq0, D1 = dA[j][p][1] + bq1, D2 = dA[j][p][2] + bq2;
                float dot = P0 * D0 + P1 * D1 + P2 * D2;
                float dsq = D0 * D0 + D1 * D1 + D2 * D2;
                if (dot < 0.0f) {
                    float s = dot / (dsq + 1e-6f);
                    P0 -= s * D0; P1 -= s * D1; P2 -= s * D2;
                }
            }
            res[0][p] = P0; res[1][p] = P1; res[2][p] = P2;
        }
        long ob = (long)b * oBS + (long)(o * 3) * N + n0 + (q << 2);
#pragma unroll
        for (int c = 0; c < 3; ++c) {
            float4 v = make_float4(res[c][0], res[c][1], res[c][2], res[c][3]);
            float4* dst = (float4*)(Out + ob + (long)c * N);
            if (accum) {
                float4 old = *dst;
                v.x += old.x; v.y += old.y; v.z += old.z; v.w += old.w;
            }
            *dst = v;
        }
    }
}

// ---------------- mean over N per (b, channel, comp) row ----------------
__global__ __launch_bounds__(256) void reduce_mean_kernel(const float* __restrict__ src, long bs,
                                                          float* __restrict__ dst, int N) {
    __shared__ float red[256];
    int row = blockIdx.x;          // row = (b*128+o)*3 + c, 0..767
    int b = row / 384; int rr = row % 384;
    const float* p = src + (long)b * bs + (long)rr * N;
    float s = 0.f;
    for (int i = threadIdx.x; i < N; i += 256) s += p[i];
    red[threadIdx.x] = s;
    __syncthreads();
    for (int st = 128; st > 0; st >>= 1) {
        if (threadIdx.x < st) red[threadIdx.x] += red[threadIdx.x + st];
        __syncthreads();
    }
    if (threadIdx.x == 0) dst[row] = red[0] / (float)N;
}

// ---------------- bias from global-mean half of Wg/Ug ----------------
// biasP[(b*128+o)*3+c] = sum_i Wg[o*256+128+i] * yg[(b*128+i)*3+c]
__global__ __launch_bounds__(256) void bias_kernel(const float* __restrict__ Wg,
                                                   const float* __restrict__ Ug,
                                                   const float* __restrict__ yg,
                                                   float* __restrict__ biasP,
                                                   float* __restrict__ biasD) {
    int t = blockIdx.x * 256 + threadIdx.x;
    if (t >= 768) return;
    int c = t % 3; int o = (t / 3) % 128; int b = t / 384;
    float sp = 0.f, sd = 0.f;
    for (int i = 0; i < 128; ++i) {
        float y = yg[((long)b * 128 + i) * 3 + c];
        sp = fmaf(Wg[o * 256 + 128 + i], y, sp);
        sd = fmaf(Ug[o * 256 + 128 + i], y, sd);
    }
    biasP[t] = sp;
    biasD[t] = sd;
}

extern "C" void kernel_launch(void* const* d_in, const int* in_sizes, int n_in,
                              void* d_out, int out_size, void* d_ws, size_t ws_size,
                              hipStream_t stream) {
    const float* x    = (const float*)d_in[0];
    const float* Win  = (const float*)d_in[1];
    const float* Uin  = (const float*)d_in[2];
    const float* Wl   = (const float*)d_in[3];
    const float* Ul   = (const float*)d_in[4];
    const float* Wg   = (const float*)d_in[5];
    const float* Ug   = (const float*)d_in[6];
    const float* Wout = (const float*)d_in[7];

    const int B = 2, N = 4096, H = 128;
    float* out0 = (float*)d_out;                 // (B,128,3) mean
    float* out1 = out0 + (long)B * H * 3;        // (B,128,3,N)

    float* ws = (float*)d_ws;
    long off = 0;
    float4* pts4 = (float4*)ws;                  off += (long)B * N * 4;
    int* idx = (int*)(ws + off);                 off += (long)B * N * 16;
    float* bufA = ws + off;                      off += (long)B * H * 3 * N;
    float* bufB = ws + off;                      off += (long)B * H * 3 * N;
    float* yg    = ws + off;                     off += B * H * 3;
    float* biasP = ws + off;                     off += B * H * 3;
    float* biasD = ws + off;                     off += B * H * 3;
    // total ~25.8 MB of workspace

    long bs128 = (long)H * 3 * N;

    prep_kernel<<<(B * N + 255) / 256, 256, 0, stream>>>(x, pts4, N, B);
    knn_kernel<<<B * (N / 16), 1024, 0, stream>>>(pts4, idx, N);
    edge_kernel<<<B * (N / 8), 256, 0, stream>>>(pts4, idx, Win, Uin, bufA, N);

    for (int l = 0; l < 4; ++l) {
        // y1 = LNA(Wl y, Ul y)
        gemm_lna_kernel<true><<<B * (N / 16), 256, 0, stream>>>(
            bufA, bs128, Wl + l * H * H, Ul + l * H * H, H,
            nullptr, nullptr, 0, bufB, bs128, H, N, 0);
        // yg = mean_N(y1); bias = Wg[:,128:] @ yg (and Ug)
        reduce_mean_kernel<<<B * H * 3, 256, 0, stream>>>(bufB, bs128, yg, N);
        bias_kernel<<<3, 256, 0, stream>>>(Wg + l * H * 256, Ug + l * H * 256, yg, biasP, biasD);
        // y2 = LNA(Wg[:, :128] y1 + biasP, Ug[:, :128] y1 + biasD)
        gemm_lna_kernel<true><<<B * (N / 16), 256, 0, stream>>>(
            bufB, bs128, Wg + l * H * 256, Ug + l * H * 256, 256,
            biasP, biasD, 1, bufA, bs128, H, N, 0);
        // out1 (+)= W_out[:, l*128:(l+1)*128] @ y2
        gemm_lna_kernel<false><<<B * (N / 16), 256, 0, stream>>>(
            bufA, bs128, Wout + l * H, nullptr, 4 * H,
            nullptr, nullptr, 0, out1, bs128, H, N, l > 0 ? 1 : 0);
    }
    reduce_mean_kernel<<<B * H * 3, 256, 0, stream>>>(out1, bs128, out0, N);
}

// Round 3
// 515.348 us; speedup vs baseline: 2.7508x; 1.3387x over previous
//
#include <hip/hip_runtime.h>
#include <hip/hip_bf16.h>
#include <cfloat>

// VecPointNet on MI355X, round 3:
//  - kNN: software-pipelined LDS reads + float threshold ballot.
//  - All 12 GEMMs -> MFMA 16x16x32 bf16 with hi/lo split (bf16x3, ~fp32 accuracy).
//    Activations stored transposed [b][c][n][k] bf16 hi/lo so B-fragments are
//    direct 16B coalesced global loads; weights pre-packed into per-lane
//    fragment order so A-fragments are direct 16B loads. No LDS in GEMM.

typedef __attribute__((ext_vector_type(8))) short short8;
typedef __attribute__((ext_vector_type(4))) float f32x4;

__device__ __forceinline__ unsigned short f2bf(float f) {
    union { float f; unsigned u; } v; v.f = f;
    unsigned r = v.u + 0x7fffu + ((v.u >> 16) & 1u);
    return (unsigned short)(r >> 16);
}
__device__ __forceinline__ float bf2f(unsigned short h) {
    union { unsigned u; float f; } v; v.u = ((unsigned)h) << 16;
    return v.f;
}

// ---------------- prep: pts4[b][n] = (x,y,z, x^2+y^2+z^2) ----------------
__global__ __launch_bounds__(256) void prep_kernel(const float* __restrict__ x,
                                                   float4* __restrict__ pts4,
                                                   int N, int B) {
    int t = blockIdx.x * 256 + threadIdx.x;
    if (t >= B * N) return;
    int b = t / N, n = t - b * N;
    const float* xb = x + (long)b * 3 * N;
    float px = xb[n], py = xb[N + n], pz = xb[2 * N + n];
    float sq = px * px + py * py + pz * pz;
    pts4[t] = make_float4(px, py, pz, sq);
}

// ---------------- knn: one wave per query, ballot-filtered top-16 ----------------
__global__ __launch_bounds__(1024) void knn_kernel(const float4* __restrict__ pts4,
                                                   int* __restrict__ idxOut, int N) {
    __shared__ float4 cbuf[4096];   // 64 KB
    int t = threadIdx.x;
    int tilesPerB = N / 16;
    int b = blockIdx.x / tilesPerB;
    int q = (blockIdx.x % tilesPerB) * 16 + (t >> 6);
    int lane = t & 63;

    for (int i = t; i < N; i += 1024) cbuf[i] = pts4[b * N + i];
    __syncthreads();

    float4 Q = cbuf[q];
    double kkey = 1e300;   // lanes 0..15: sorted ascending exact keys
    float  kd2  = FLT_MAX; // shadow d2 floats (same permutation)
    double T = 1e300;
    float  Tf = FLT_MAX;

    float4 Cn = cbuf[lane];                       // pipelined read
    for (int c0 = 0; c0 < N; c0 += 64) {
        float4 C = Cn;
        Cn = cbuf[((c0 + 64) & (N - 1)) + lane];  // prefetch next chunk
        float dot = Q.x * C.x + Q.y * C.y + Q.z * C.z;
        float d2 = Q.w + C.w - 2.0f * dot;        // same formula as reference
        unsigned long long mask = __ballot(d2 <= Tf);
        if (mask) {
            unsigned u = __float_as_uint(d2);
            u ^= (unsigned)((int)u >> 31) | 0x80000000u;   // orderable uint
            double key = (double)u * 4096.0 + (double)(c0 + lane);
            do {
                int src = __ffsll(mask) - 1;
                mask &= mask - 1;
                double vb = __shfl(key, src);
                float vd2 = __shfl(d2, src);
                if (vb < T) {                      // uniform (exact) recheck
                    double km1 = __shfl_up(kkey, 1);
                    float  dm1 = __shfl_up(kd2, 1);
                    if (lane == 0) { km1 = -1.0; dm1 = 0.f; }
                    bool below = (vb <= km1);
                    bool lt = (vb < kkey);
                    double kn = below ? km1 : (lt ? vb : kkey);
                    float  dn = below ? dm1 : (lt ? vd2 : kd2);
                    if (lane < 16) { kkey = kn; kd2 = dn; }
                    T = __shfl(kkey, 15);
                    Tf = __shfl(kd2, 15);
                }
            } while (mask);
        }
    }
    if (lane < 16) {
        long long kl = (long long)kkey;            // exact (key < 2^44)
        idxOut[(b * N + q) * 16 + lane] = (int)(kl & 4095);
    }
}

// ---------------- edge features + input LNA + mean over K -> Ytr bf16 hi/lo ----------------
// Output layout: Y[((b*3+c)*4096 + n)*128 + o], hi and lo arrays.
__global__ __launch_bounds__(256) void edge_kernel(const float4* __restrict__ pts4,
                                                   const int* __restrict__ idx,
                                                   const float* __restrict__ Win,
                                                   const float* __restrict__ Uin,
                                                   unsigned short* __restrict__ Yh,
                                                   unsigned short* __restrict__ Yl,
                                                   int N) {
    __shared__ float4 nbuf[8][16];
    __shared__ float4 cpt[8];
    int nTiles = N / 8;
    int b = blockIdx.x / nTiles;
    int n0 = (blockIdx.x % nTiles) * 8;
    int t = threadIdx.x;
    if (t < 128) {
        int pl = t >> 4, k = t & 15;
        int nb = idx[(b * N + n0 + pl) * 16 + k];
        nbuf[pl][k] = pts4[b * N + nb];
    } else if (t < 136) {
        cpt[t - 128] = pts4[b * N + n0 + (t - 128)];
    }
    __syncthreads();
    int o = t & 127, h = t >> 7;
    float w0 = Win[o * 3], w1 = Win[o * 3 + 1], w2 = Win[o * 3 + 2];
    float u0 = Uin[o * 3], u1 = Uin[o * 3 + 1], u2 = Uin[o * 3 + 2];
    for (int pl = h * 4; pl < h * 4 + 4; ++pl) {
        float4 c4 = cpt[pl];
        float inv = 1.0f / fmaxf(sqrtf(c4.w), 1e-12f);
        float ax = c4.x * inv, ay = c4.y * inv, az = c4.z * inv;
        float a0 = 0.f, a1 = 0.f, a2 = 0.f;
        for (int k = 0; k < 16; ++k) {
            float4 nb = nbuf[pl][k];
            float cr0 = ay * nb.z - az * nb.y;
            float cr1 = az * nb.x - ax * nb.z;
            float cr2 = ax * nb.y - ay * nb.x;
            float df0 = nb.x - c4.x, df1 = nb.y - c4.y, df2 = nb.z - c4.z;
            float P0 = w0 * cr0 + w1 * df0 + w2 * c4.x;
            float P1 = w0 * cr1 + w1 * df1 + w2 * c4.y;
            float P2 = w0 * cr2 + w1 * df2 + w2 * c4.z;
            float D0 = u0 * cr0 + u1 * df0 + u2 * c4.x;
            float D1 = u0 * cr1 + u1 * df1 + u2 * c4.y;
            float D2 = u0 * cr2 + u1 * df2 + u2 * c4.z;
            float dot = P0 * D0 + P1 * D1 + P2 * D2;
            float dsq = D0 * D0 + D1 * D1 + D2 * D2;
            if (dot < 0.0f) {
                float s = dot / (dsq + 1e-6f);
                P0 -= s * D0; P1 -= s * D1; P2 -= s * D2;
            }
            a0 += P0; a1 += P1; a2 += P2;
        }
        float vals[3] = { a0 * (1.0f / 16.0f), a1 * (1.0f / 16.0f), a2 * (1.0f / 16.0f) };
        long n = n0 + pl;
#pragma unroll
        for (int c = 0; c < 3; ++c) {
            long off = ((long)(b * 3 + c) * 4096 + n) * 128 + o;
            unsigned short hh = f2bf(vals[c]);
            Yh[off] = hh;
            Yl[off] = f2bf(vals[c] - bf2f(hh));
        }
    }
}

// ---------------- weight pack: per-lane MFMA fragment order, hi/lo ----------------
// gemms 0..3: layer Wl/Ul (M=256,ldw=128); 4..7: Wg/Ug first half (M=256,ldw=256);
// 8..11: Wout cols [g-8]*128.. (M=128,ldw=512).
// element r within gemm: r = ((ks*MF + mf)*64 + lane)*8 + j ; m = mf*16+(lane&15);
// k = ks*32 + 8*(lane>>4) + j.
__global__ __launch_bounds__(256) void pack_kernel(const float* __restrict__ Wl,
                                                   const float* __restrict__ Ul,
                                                   const float* __restrict__ Wg,
                                                   const float* __restrict__ Ug,
                                                   const float* __restrict__ Wout,
                                                   unsigned short* __restrict__ Ah,
                                                   unsigned short* __restrict__ Al) {
    int t = blockIdx.x * 256 + threadIdx.x;     // 0..327679
    int g, r, M; long base;
    if (t < 262144) { g = t >> 15; r = t & 32767; M = 256; base = (long)g << 15; }
    else { int t2 = t - 262144; g = 8 + (t2 >> 14); r = t2 & 16383; M = 128;
           base = 262144 + (long)(g - 8) * 16384; }
    int MF = M >> 4;
    int ks = r / (MF * 512);
    int mf = (r >> 9) % MF;
    int lane = (r >> 3) & 63;
    int j = r & 7;
    int m = mf * 16 + (lane & 15);
    int k = ks * 32 + ((lane >> 4) << 3) + j;
    const float* src; int ldw; int row;
    if (g < 4) {
        ldw = 128; row = m & 127;
        src = (m < 128) ? (Wl + (long)g * 128 * 128) : (Ul + (long)g * 128 * 128);
    } else if (g < 8) {
        ldw = 256; row = m & 127;
        int l = g - 4;
        src = (m < 128) ? (Wg + (long)l * 128 * 256) : (Ug + (long)l * 128 * 256);
    } else {
        ldw = 512; row = m;
        src = Wout + (g - 8) * 128;
    }
    float v = src[(long)row * ldw + k];
    unsigned short h = f2bf(v);
    Ah[base + r] = h;
    Al[base + r] = f2bf(v - bf2f(h));
}

// ---------------- MFMA GEMM, bf16x3, fragments direct from global ----------------
// MODE 0: LNA, no bias  (M=256: P rows 0..127 = W, D rows 128..255 = U)
// MODE 1: LNA + bias
// MODE 2: plain, M=128, fp32 output [b][o][c][n] with optional accumulate
// Grid: 256 blocks (b*128 + tile), 512 threads (8 waves: mg = w>>1, ng = w&1).
template<int MODE>
__global__ __launch_bounds__(512, 1) void gemm_kernel(
    const unsigned short* __restrict__ Aph, const unsigned short* __restrict__ Apl, long aOff,
    const unsigned short* __restrict__ Bh, const unsigned short* __restrict__ Bl,
    const float* __restrict__ biasP, const float* __restrict__ biasD,
    unsigned short* __restrict__ Oh, unsigned short* __restrict__ Ol,
    float* __restrict__ Ofp, int accum)
{
    const int N = 4096;
    int t = threadIdx.x;
    int lane = t & 63, w = t >> 6;
    int mg = w >> 1, ng = w & 1;
    int b = blockIdx.x >> 7;
    int tile = blockIdx.x & 127;
    int n0 = tile * 32 + ng * 16;
    int ncol = n0 + (lane & 15);
    int kq = (lane >> 4) << 3;

    const int MF = (MODE == 2) ? 8 : 16;

    f32x4 accP[2][3] = {};
    f32x4 accD[2][3] = {};

    const unsigned short* AhB = Aph + aOff;
    const unsigned short* AlB = Apl + aOff;

#pragma unroll
    for (int ks = 0; ks < 4; ++ks) {
        short8 bh[3], bl[3];
#pragma unroll
        for (int c = 0; c < 3; ++c) {
            long boff = ((long)(b * 3 + c) * N + ncol) * 128 + ks * 32 + kq;
            bh[c] = *(const short8*)(Bh + boff);
            bl[c] = *(const short8*)(Bl + boff);
        }
#pragma unroll
        for (int pi = 0; pi < 2; ++pi) {
            int mf = 2 * mg + pi;
            long aoffP = (((long)ks * MF + mf) * 64 + lane) * 8;
            short8 ahP = *(const short8*)(AhB + aoffP);
            short8 alP = *(const short8*)(AlB + aoffP);
#pragma unroll
            for (int c = 0; c < 3; ++c) {
                accP[pi][c] = __builtin_amdgcn_mfma_f32_16x16x32_bf16(ahP, bh[c], accP[pi][c], 0, 0, 0);
                accP[pi][c] = __builtin_amdgcn_mfma_f32_16x16x32_bf16(ahP, bl[c], accP[pi][c], 0, 0, 0);
                accP[pi][c] = __builtin_amdgcn_mfma_f32_16x16x32_bf16(alP, bh[c], accP[pi][c], 0, 0, 0);
            }
            if (MODE != 2) {
                long aoffD = (((long)ks * MF + (8 + mf)) * 64 + lane) * 8;
                short8 ahD = *(const short8*)(AhB + aoffD);
                short8 alD = *(const short8*)(AlB + aoffD);
#pragma unroll
                for (int c = 0; c < 3; ++c) {
                    accD[pi][c] = __builtin_amdgcn_mfma_f32_16x16x32_bf16(ahD, bh[c], accD[pi][c], 0, 0, 0);
                    accD[pi][c] = __builtin_amdgcn_mfma_f32_16x16x32_bf16(ahD, bl[c], accD[pi][c], 0, 0, 0);
                    accD[pi][c] = __builtin_amdgcn_mfma_f32_16x16x32_bf16(alD, bh[c], accD[pi][c], 0, 0, 0);
                }
            }
        }
    }

#pragma unroll
    for (int pi = 0; pi < 2; ++pi) {
        int obase = 32 * mg + 16 * pi + ((lane >> 4) << 2);
        if (MODE != 2) {
            unsigned short hs[3][4], ls[3][4];
#pragma unroll
            for (int r = 0; r < 4; ++r) {
                int o = obase + r;
                float P[3], D[3];
#pragma unroll
                for (int c = 0; c < 3; ++c) {
                    P[c] = accP[pi][c][r];
                    D[c] = accD[pi][c][r];
                    if (MODE == 1) {
                        long bb = ((long)(b * 128 + o)) * 3 + c;
                        P[c] += biasP[bb];
                        D[c] += biasD[bb];
                    }
                }
                float dot = P[0] * D[0] + P[1] * D[1] + P[2] * D[2];
                float dsq = D[0] * D[0] + D[1] * D[1] + D[2] * D[2];
                if (dot < 0.0f) {
                    float s = dot / (dsq + 1e-6f);
                    P[0] -= s * D[0]; P[1] -= s * D[1]; P[2] -= s * D[2];
                }
#pragma unroll
                for (int c = 0; c < 3; ++c) {
                    unsigned short hh = f2bf(P[c]);
                    hs[c][r] = hh;
                    ls[c][r] = f2bf(P[c] - bf2f(hh));
                }
            }
#pragma unroll
            for (int c = 0; c < 3; ++c) {
                long ooff = ((long)(b * 3 + c) * N + ncol) * 128 + obase;
                *(ushort4*)(Oh + ooff) = make_ushort4(hs[c][0], hs[c][1], hs[c][2], hs[c][3]);
                *(ushort4*)(Ol + ooff) = make_ushort4(ls[c][0], ls[c][1], ls[c][2], ls[c][3]);
            }
        } else {
#pragma unroll
            for (int r = 0; r < 4; ++r) {
                int o = obase + r;
#pragma unroll
                for (int c = 0; c < 3; ++c) {
                    long off = ((long)(b * 128 + o) * 3 + c) * N + ncol;
                    float v = accP[pi][c][r];
                    if (accum) v += Ofp[off];
                    Ofp[off] = v;
                }
            }
        }
    }
}

// ---------------- yg = mean over n of y1 (bf16 hi/lo, transposed layout) ----------------
// grid = 6 blocks (b*3+c), 1024 threads: o4=(t&31)*4, stripe=t>>5 (32 x 128 rows).
__global__ __launch_bounds__(1024) void reduce_yg_kernel(const unsigned short* __restrict__ Yh,
                                                         const unsigned short* __restrict__ Yl,
                                                         float* __restrict__ yg) {
    __shared__ float part[32][128];
    int bc = blockIdx.x;
    int t = threadIdx.x;
    int o4 = (t & 31) * 4, st = t >> 5;
    float s0 = 0, s1 = 0, s2 = 0, s3 = 0;
    for (int n = st * 128; n < st * 128 + 128; ++n) {
        long off = ((long)bc * 4096 + n) * 128 + o4;
        ushort4 h = *(const ushort4*)(Yh + off);
        ushort4 l = *(const ushort4*)(Yl + off);
        s0 += bf2f(h.x) + bf2f(l.x);
        s1 += bf2f(h.y) + bf2f(l.y);
        s2 += bf2f(h.z) + bf2f(l.z);
        s3 += bf2f(h.w) + bf2f(l.w);
    }
    part[st][o4] = s0; part[st][o4 + 1] = s1; part[st][o4 + 2] = s2; part[st][o4 + 3] = s3;
    __syncthreads();
    if (t < 128) {
        float s = 0;
#pragma unroll
        for (int k = 0; k < 32; ++k) s += part[k][t];
        int b = bc / 3, c = bc % 3;
        yg[((long)(b * 128) + t) * 3 + c] = s * (1.0f / 4096.0f);
    }
}

// ---------------- bias from global-mean half of Wg/Ug ----------------
__global__ __launch_bounds__(256) void bias_kernel(const float* __restrict__ Wg,
                                                   const float* __restrict__ Ug,
                                                   const float* __restrict__ yg,
                                                   float* __restrict__ biasP,
                                                   float* __restrict__ biasD) {
    int t = blockIdx.x * 256 + threadIdx.x;
    if (t >= 768) return;
    int c = t % 3; int o = (t / 3) % 128; int b = t / 384;
    float sp = 0.f, sd = 0.f;
    for (int i = 0; i < 128; ++i) {
        float y = yg[((long)b * 128 + i) * 3 + c];
        sp = fmaf(Wg[o * 256 + 128 + i], y, sp);
        sd = fmaf(Ug[o * 256 + 128 + i], y, sd);
    }
    biasP[t] = sp;
    biasD[t] = sd;
}

// ---------------- mean over N per (b, o, c) row of fp32 out1 ----------------
__global__ __launch_bounds__(256) void reduce_mean_kernel(const float* __restrict__ src, long bs,
                                                          float* __restrict__ dst, int N) {
    __shared__ float red[256];
    int row = blockIdx.x;          // (b*128+o)*3 + c
    int b = row / 384; int rr = row % 384;
    const float* p = src + (long)b * bs + (long)rr * N;
    float s = 0.f;
    for (int i = threadIdx.x; i < N; i += 256) s += p[i];
    red[threadIdx.x] = s;
    __syncthreads();
    for (int st = 128; st > 0; st >>= 1) {
        if (threadIdx.x < st) red[threadIdx.x] += red[threadIdx.x + st];
        __syncthreads();
    }
    if (threadIdx.x == 0) dst[row] = red[0] / (float)N;
}

extern "C" void kernel_launch(void* const* d_in, const int* in_sizes, int n_in,
                              void* d_out, int out_size, void* d_ws, size_t ws_size,
                              hipStream_t stream) {
    const float* x    = (const float*)d_in[0];
    const float* Win  = (const float*)d_in[1];
    const float* Uin  = (const float*)d_in[2];
    const float* Wl   = (const float*)d_in[3];
    const float* Ul   = (const float*)d_in[4];
    const float* Wg   = (const float*)d_in[5];
    const float* Ug   = (const float*)d_in[6];
    const float* Wout = (const float*)d_in[7];

    const int B = 2, N = 4096, H = 128;
    float* out0 = (float*)d_out;                 // (B,128,3) mean
    float* out1 = out0 + (long)B * H * 3;        // (B,128,3,N) fp32

    float* ws = (float*)d_ws;
    long off = 0;
    float4* pts4 = (float4*)ws;                  off += (long)B * N * 4;
    int* idx = (int*)(ws + off);                 off += (long)B * N * 16;
    const long ACT = (long)B * 3 * N * H;        // ushort count = 3,145,728 (=> /2 in floats)
    unsigned short* f0h = (unsigned short*)(ws + off);  off += ACT / 2;
    unsigned short* f0l = (unsigned short*)(ws + off);  off += ACT / 2;
    unsigned short* y1h = (unsigned short*)(ws + off);  off += ACT / 2;
    unsigned short* y1l = (unsigned short*)(ws + off);  off += ACT / 2;
    unsigned short* Aph = (unsigned short*)(ws + off);  off += 327680 / 2;
    unsigned short* Apl = (unsigned short*)(ws + off);  off += 327680 / 2;
    float* yg    = ws + off;                     off += B * H * 3;
    float* biasP = ws + off;                     off += B * H * 3;
    float* biasD = ws + off;                     off += B * H * 3;
    // ~27 MB of workspace

    long bs128 = (long)H * 3 * N;

    prep_kernel<<<(B * N + 255) / 256, 256, 0, stream>>>(x, pts4, N, B);
    knn_kernel<<<B * (N / 16), 1024, 0, stream>>>(pts4, idx, N);
    edge_kernel<<<B * (N / 8), 256, 0, stream>>>(pts4, idx, Win, Uin, f0h, f0l, N);
    pack_kernel<<<1280, 256, 0, stream>>>(Wl, Ul, Wg, Ug, Wout, Aph, Apl);

    for (int l = 0; l < 4; ++l) {
        // y1 = LNA(Wl y2prev, Ul y2prev)   (y2prev = f0 buffers)
        gemm_kernel<0><<<256, 512, 0, stream>>>(
            Aph, Apl, (long)l * 32768, f0h, f0l, nullptr, nullptr,
            y1h, y1l, nullptr, 0);
        // yg = mean_N(y1); bias = Wg[:,128:] @ yg (and Ug)
        reduce_yg_kernel<<<6, 1024, 0, stream>>>(y1h, y1l, yg);
        bias_kernel<<<3, 256, 0, stream>>>(Wg + (long)l * H * 256, Ug + (long)l * H * 256,
                                           yg, biasP, biasD);
        // y2 = LNA(Wg[:, :128] y1 + biasP, Ug[:, :128] y1 + biasD) -> f0 buffers
        gemm_kernel<1><<<256, 512, 0, stream>>>(
            Aph, Apl, (long)(4 + l) * 32768, y1h, y1l, biasP, biasD,
            f0h, f0l, nullptr, 0);
        // out1 (+)= W_out[:, l*128:(l+1)*128] @ y2
        gemm_kernel<2><<<256, 512, 0, stream>>>(
            Aph, Apl, 262144 + (long)l * 16384, f0h, f0l, nullptr, nullptr,
            nullptr, nullptr, out1, l > 0 ? 1 : 0);
    }
    reduce_mean_kernel<<<B * H * 3, 256, 0, stream>>>(out1, bs128, out0, N);
}

// Round 4
// 355.262 us; speedup vs baseline: 3.9904x; 1.4506x over previous
//
#include <hip/hip_runtime.h>
#include <hip/hip_bf16.h>
#include <cfloat>

// VecPointNet on MI355X, round 4:
//  - kNN reverted to round-2 version (prefetch variant regressed 85->115us).
//  - reduce_yg split into two stages (was 6-block grid reading 12.6MB -> ~160us).
//  - Wout GEMM fused into the Wg LNA-GEMM via LDS y2 staging (removes 4 dispatches
//    + 12.6MB roundtrip per layer).

typedef __attribute__((ext_vector_type(8))) short short8;
typedef __attribute__((ext_vector_type(4))) float f32x4;

__device__ __forceinline__ unsigned short f2bf(float f) {
    union { float f; unsigned u; } v; v.f = f;
    unsigned r = v.u + 0x7fffu + ((v.u >> 16) & 1u);
    return (unsigned short)(r >> 16);
}
__device__ __forceinline__ float bf2f(unsigned short h) {
    union { unsigned u; float f; } v; v.u = ((unsigned)h) << 16;
    return v.f;
}

// ---------------- prep: pts4[b][n] = (x,y,z, x^2+y^2+z^2) ----------------
__global__ __launch_bounds__(256) void prep_kernel(const float* __restrict__ x,
                                                   float4* __restrict__ pts4,
                                                   int N, int B) {
    int t = blockIdx.x * 256 + threadIdx.x;
    if (t >= B * N) return;
    int b = t / N, n = t - b * N;
    const float* xb = x + (long)b * 3 * N;
    float px = xb[n], py = xb[N + n], pz = xb[2 * N + n];
    float sq = px * px + py * py + pz * pz;
    pts4[t] = make_float4(px, py, pz, sq);
}

// ---------------- knn (round-2 version): one wave per query, ballot top-16 ----------------
__global__ __launch_bounds__(1024) void knn_kernel(const float4* __restrict__ pts4,
                                                   int* __restrict__ idxOut, int N) {
    __shared__ float4 cbuf[4096];   // 64 KB
    int t = threadIdx.x;
    int tilesPerB = N / 16;
    int b = blockIdx.x / tilesPerB;
    int q = (blockIdx.x % tilesPerB) * 16 + (t >> 6);
    int lane = t & 63;

    for (int i = t; i < N; i += 1024) cbuf[i] = pts4[b * N + i];
    __syncthreads();

    float4 Q = cbuf[q];
    double k = 1e300;     // lanes 0..15: sorted ascending top-16 keys
    double T = 1e300;     // current 16th-best key (uniform)

    for (int c0 = 0; c0 < N; c0 += 64) {
        float4 C = cbuf[c0 + lane];
        float dot = Q.x * C.x + Q.y * C.y + Q.z * C.z;
        float d2 = Q.w + C.w - 2.0f * dot;          // same formula as reference
        unsigned u = __float_as_uint(d2);
        u ^= (unsigned)((int)u >> 31) | 0x80000000u; // orderable uint
        double key = (double)u * 4096.0 + (double)(c0 + lane);
        unsigned long long mask = __ballot(key < T);
        while (mask) {
            int src = __ffsll(mask) - 1;
            mask &= mask - 1;
            double vb = __shfl(key, src);
            if (vb < T) {                            // uniform branch (stale-mask recheck)
                double km1 = __shfl_up(k, 1);
                if (lane == 0) km1 = -1.0;
                double kn = (vb <= km1) ? km1 : ((vb < k) ? vb : k);
                if (lane < 16) k = kn;
                T = __shfl(k, 15);
            }
        }
    }
    if (lane < 16) {
        long long kl = (long long)k;                 // exact (key < 2^44)
        idxOut[(b * N + q) * 16 + lane] = (int)(kl & 4095);
    }
}

// ---------------- edge features + input LNA + mean over K -> Ytr bf16 hi/lo ----------------
__global__ __launch_bounds__(256) void edge_kernel(const float4* __restrict__ pts4,
                                                   const int* __restrict__ idx,
                                                   const float* __restrict__ Win,
                                                   const float* __restrict__ Uin,
                                                   unsigned short* __restrict__ Yh,
                                                   unsigned short* __restrict__ Yl,
                                                   int N) {
    __shared__ float4 nbuf[8][16];
    __shared__ float4 cpt[8];
    int nTiles = N / 8;
    int b = blockIdx.x / nTiles;
    int n0 = (blockIdx.x % nTiles) * 8;
    int t = threadIdx.x;
    if (t < 128) {
        int pl = t >> 4, k = t & 15;
        int nb = idx[(b * N + n0 + pl) * 16 + k];
        nbuf[pl][k] = pts4[b * N + nb];
    } else if (t < 136) {
        cpt[t - 128] = pts4[b * N + n0 + (t - 128)];
    }
    __syncthreads();
    int o = t & 127, h = t >> 7;
    float w0 = Win[o * 3], w1 = Win[o * 3 + 1], w2 = Win[o * 3 + 2];
    float u0 = Uin[o * 3], u1 = Uin[o * 3 + 1], u2 = Uin[o * 3 + 2];
    for (int pl = h * 4; pl < h * 4 + 4; ++pl) {
        float4 c4 = cpt[pl];
        float inv = 1.0f / fmaxf(sqrtf(c4.w), 1e-12f);
        float ax = c4.x * inv, ay = c4.y * inv, az = c4.z * inv;
        float a0 = 0.f, a1 = 0.f, a2 = 0.f;
        for (int k = 0; k < 16; ++k) {
            float4 nb = nbuf[pl][k];
            float cr0 = ay * nb.z - az * nb.y;
            float cr1 = az * nb.x - ax * nb.z;
            float cr2 = ax * nb.y - ay * nb.x;
            float df0 = nb.x - c4.x, df1 = nb.y - c4.y, df2 = nb.z - c4.z;
            float P0 = w0 * cr0 + w1 * df0 + w2 * c4.x;
            float P1 = w0 * cr1 + w1 * df1 + w2 * c4.y;
            float P2 = w0 * cr2 + w1 * df2 + w2 * c4.z;
            float D0 = u0 * cr0 + u1 * df0 + u2 * c4.x;
            float D1 = u0 * cr1 + u1 * df1 + u2 * c4.y;
            float D2 = u0 * cr2 + u1 * df2 + u2 * c4.z;
            float dot = P0 * D0 + P1 * D1 + P2 * D2;
            float dsq = D0 * D0 + D1 * D1 + D2 * D2;
            if (dot < 0.0f) {
                float s = dot / (dsq + 1e-6f);
                P0 -= s * D0; P1 -= s * D1; P2 -= s * D2;
            }
            a0 += P0; a1 += P1; a2 += P2;
        }
        float vals[3] = { a0 * (1.0f / 16.0f), a1 * (1.0f / 16.0f), a2 * (1.0f / 16.0f) };
        long n = n0 + pl;
#pragma unroll
        for (int c = 0; c < 3; ++c) {
            long off = ((long)(b * 3 + c) * 4096 + n) * 128 + o;
            unsigned short hh = f2bf(vals[c]);
            Yh[off] = hh;
            Yl[off] = f2bf(vals[c] - bf2f(hh));
        }
    }
}

// ---------------- weight pack: per-lane MFMA fragment order, hi/lo ----------------
__global__ __launch_bounds__(256) void pack_kernel(const float* __restrict__ Wl,
                                                   const float* __restrict__ Ul,
                                                   const float* __restrict__ Wg,
                                                   const float* __restrict__ Ug,
                                                   const float* __restrict__ Wout,
                                                   unsigned short* __restrict__ Ah,
                                                   unsigned short* __restrict__ Al) {
    int t = blockIdx.x * 256 + threadIdx.x;     // 0..327679
    int g, r, M; long base;
    if (t < 262144) { g = t >> 15; r = t & 32767; M = 256; base = (long)g << 15; }
    else { int t2 = t - 262144; g = 8 + (t2 >> 14); r = t2 & 16383; M = 128;
           base = 262144 + (long)(g - 8) * 16384; }
    int MF = M >> 4;
    int ks = r / (MF * 512);
    int mf = (r >> 9) % MF;
    int lane = (r >> 3) & 63;
    int j = r & 7;
    int m = mf * 16 + (lane & 15);
    int k = ks * 32 + ((lane >> 4) << 3) + j;
    const float* src; int ldw; int row;
    if (g < 4) {
        ldw = 128; row = m & 127;
        src = (m < 128) ? (Wl + (long)g * 128 * 128) : (Ul + (long)g * 128 * 128);
    } else if (g < 8) {
        ldw = 256; row = m & 127;
        int l = g - 4;
        src = (m < 128) ? (Wg + (long)l * 128 * 256) : (Ug + (long)l * 128 * 256);
    } else {
        ldw = 512; row = m;
        src = Wout + (g - 8) * 128;
    }
    float v = src[(long)row * ldw + k];
    unsigned short h = f2bf(v);
    Ah[base + r] = h;
    Al[base + r] = f2bf(v - bf2f(h));
}

// ---------------- MFMA GEMM, bf16x3, fragments direct from global ----------------
// MODE 0: LNA, no bias, no fusion.
// MODE 1: LNA + bias + fused Wout GEMM (y2 staged in LDS, Wout partial -> Ofp).
// Grid: 256 blocks (b*128 + tile), 512 threads (8 waves: mg = w>>1, ng = w&1).
template<int MODE>
__global__ __launch_bounds__(512, 1) void gemm_kernel(
    const unsigned short* __restrict__ Aph, const unsigned short* __restrict__ Apl,
    long aOff, long aOffOut,
    const unsigned short* __restrict__ Bh, const unsigned short* __restrict__ Bl,
    const float* __restrict__ biasP, const float* __restrict__ biasD,
    unsigned short* __restrict__ Oh, unsigned short* __restrict__ Ol,
    float* __restrict__ Ofp, int accum)
{
    const int N = 4096;
    // y2 staging for fused Wout: [ng][c][hi/lo][ ((k>>3)*16 + col)*8 + (k&7) ]
    __shared__ unsigned short ylds[MODE == 1 ? 2 : 1][3][2][2048];
    int t = threadIdx.x;
    int lane = t & 63, w = t >> 6;
    int mg = w >> 1, ng = w & 1;
    int b = blockIdx.x >> 7;
    int tile = blockIdx.x & 127;
    int n0 = tile * 32 + ng * 16;
    int ncol = n0 + (lane & 15);
    int kq = (lane >> 4) << 3;

    f32x4 accP[2][3] = {};
    f32x4 accD[2][3] = {};

    const unsigned short* AhB = Aph + aOff;
    const unsigned short* AlB = Apl + aOff;

#pragma unroll
    for (int ks = 0; ks < 4; ++ks) {
        short8 bh[3], bl[3];
#pragma unroll
        for (int c = 0; c < 3; ++c) {
            long boff = ((long)(b * 3 + c) * N + ncol) * 128 + ks * 32 + kq;
            bh[c] = *(const short8*)(Bh + boff);
            bl[c] = *(const short8*)(Bl + boff);
        }
#pragma unroll
        for (int pi = 0; pi < 2; ++pi) {
            int mf = 2 * mg + pi;
            long aoffP = (((long)ks * 16 + mf) * 64 + lane) * 8;
            short8 ahP = *(const short8*)(AhB + aoffP);
            short8 alP = *(const short8*)(AlB + aoffP);
#pragma unroll
            for (int c = 0; c < 3; ++c) {
                accP[pi][c] = __builtin_amdgcn_mfma_f32_16x16x32_bf16(ahP, bh[c], accP[pi][c], 0, 0, 0);
                accP[pi][c] = __builtin_amdgcn_mfma_f32_16x16x32_bf16(ahP, bl[c], accP[pi][c], 0, 0, 0);
                accP[pi][c] = __builtin_amdgcn_mfma_f32_16x16x32_bf16(alP, bh[c], accP[pi][c], 0, 0, 0);
            }
            long aoffD = (((long)ks * 16 + (8 + mf)) * 64 + lane) * 8;
            short8 ahD = *(const short8*)(AhB + aoffD);
            short8 alD = *(const short8*)(AlB + aoffD);
#pragma unroll
            for (int c = 0; c < 3; ++c) {
                accD[pi][c] = __builtin_amdgcn_mfma_f32_16x16x32_bf16(ahD, bh[c], accD[pi][c], 0, 0, 0);
                accD[pi][c] = __builtin_amdgcn_mfma_f32_16x16x32_bf16(ahD, bl[c], accD[pi][c], 0, 0, 0);
                accD[pi][c] = __builtin_amdgcn_mfma_f32_16x16x32_bf16(alD, bh[c], accD[pi][c], 0, 0, 0);
            }
        }
    }

#pragma unroll
    for (int pi = 0; pi < 2; ++pi) {
        int obase = 32 * mg + 16 * pi + ((lane >> 4) << 2);
        unsigned short hs[3][4], ls[3][4];
#pragma unroll
        for (int r = 0; r < 4; ++r) {
            int o = obase + r;
            float P[3], D[3];
#pragma unroll
            for (int c = 0; c < 3; ++c) {
                P[c] = accP[pi][c][r];
                D[c] = accD[pi][c][r];
                if (MODE == 1) {
                    long bb = ((long)(b * 128 + o)) * 3 + c;
                    P[c] += biasP[bb];
                    D[c] += biasD[bb];
                }
            }
            float dot = P[0] * D[0] + P[1] * D[1] + P[2] * D[2];
            float dsq = D[0] * D[0] + D[1] * D[1] + D[2] * D[2];
            if (dot < 0.0f) {
                float s = dot / (dsq + 1e-6f);
                P[0] -= s * D[0]; P[1] -= s * D[1]; P[2] -= s * D[2];
            }
#pragma unroll
            for (int c = 0; c < 3; ++c) {
                unsigned short hh = f2bf(P[c]);
                hs[c][r] = hh;
                ls[c][r] = f2bf(P[c] - bf2f(hh));
            }
        }
#pragma unroll
        for (int c = 0; c < 3; ++c) {
            long ooff = ((long)(b * 3 + c) * N + ncol) * 128 + obase;
            *(ushort4*)(Oh + ooff) = make_ushort4(hs[c][0], hs[c][1], hs[c][2], hs[c][3]);
            *(ushort4*)(Ol + ooff) = make_ushort4(ls[c][0], ls[c][1], ls[c][2], ls[c][3]);
            if (MODE == 1) {
#pragma unroll
                for (int r = 0; r < 4; ++r) {
                    int o = obase + r;
                    int li = ((o >> 3) << 7) + ((lane & 15) << 3) + (o & 7);
                    ylds[ng][c][0][li] = hs[c][r];
                    ylds[ng][c][1][li] = ls[c][r];
                }
            }
        }
    }

    if (MODE == 1) {
        __syncthreads();
        f32x4 accO[2][3] = {};
        const unsigned short* AoH = Aph + aOffOut;
        const unsigned short* AoL = Apl + aOffOut;
#pragma unroll
        for (int ks = 0; ks < 4; ++ks) {
            short8 yh[3], yl[3];
            int li = (((ks << 2) + (lane >> 4)) << 7) + ((lane & 15) << 3);
#pragma unroll
            for (int c = 0; c < 3; ++c) {
                yh[c] = *(const short8*)&ylds[ng][c][0][li];
                yl[c] = *(const short8*)&ylds[ng][c][1][li];
            }
#pragma unroll
            for (int pi = 0; pi < 2; ++pi) {
                int mf = 2 * mg + pi;
                long aoff = (((long)ks * 8 + mf) * 64 + lane) * 8;
                short8 ah = *(const short8*)(AoH + aoff);
                short8 al = *(const short8*)(AoL + aoff);
#pragma unroll
                for (int c = 0; c < 3; ++c) {
                    accO[pi][c] = __builtin_amdgcn_mfma_f32_16x16x32_bf16(ah, yh[c], accO[pi][c], 0, 0, 0);
                    accO[pi][c] = __builtin_amdgcn_mfma_f32_16x16x32_bf16(ah, yl[c], accO[pi][c], 0, 0, 0);
                    accO[pi][c] = __builtin_amdgcn_mfma_f32_16x16x32_bf16(al, yh[c], accO[pi][c], 0, 0, 0);
                }
            }
        }
#pragma unroll
        for (int pi = 0; pi < 2; ++pi) {
            int obase = 32 * mg + 16 * pi + ((lane >> 4) << 2);
#pragma unroll
            for (int r = 0; r < 4; ++r) {
                int o = obase + r;
#pragma unroll
                for (int c = 0; c < 3; ++c) {
                    long off = ((long)(b * 128 + o) * 3 + c) * N + ncol;
                    float v = accO[pi][c][r];
                    if (accum) v += Ofp[off];
                    Ofp[off] = v;
                }
            }
        }
    }
}

// ---------------- yg reduction stage 1: 192 blocks over (bc, n-segment) ----------------
__global__ __launch_bounds__(256) void reduce_yg1_kernel(const unsigned short* __restrict__ Yh,
                                                         const unsigned short* __restrict__ Yl,
                                                         float* __restrict__ part) {
    __shared__ float red[8][128];
    int bc = blockIdx.x >> 5, seg = blockIdx.x & 31;
    int t = threadIdx.x;
    int o4 = (t & 31) * 4, st = t >> 5;
    int n0 = seg * 128 + st * 16;
    float s0 = 0, s1 = 0, s2 = 0, s3 = 0;
    for (int n = n0; n < n0 + 16; ++n) {
        long off = ((long)bc * 4096 + n) * 128 + o4;
        ushort4 h = *(const ushort4*)(Yh + off);
        ushort4 l = *(const ushort4*)(Yl + off);
        s0 += bf2f(h.x) + bf2f(l.x);
        s1 += bf2f(h.y) + bf2f(l.y);
        s2 += bf2f(h.z) + bf2f(l.z);
        s3 += bf2f(h.w) + bf2f(l.w);
    }
    red[st][o4] = s0; red[st][o4 + 1] = s1; red[st][o4 + 2] = s2; red[st][o4 + 3] = s3;
    __syncthreads();
    if (t < 128) {
        float s = 0;
#pragma unroll
        for (int k = 0; k < 8; ++k) s += red[k][t];
        part[((long)bc * 32 + seg) * 128 + t] = s;
    }
}

// ---------------- yg reduction stage 2 ----------------
__global__ __launch_bounds__(128) void reduce_yg2_kernel(const float* __restrict__ part,
                                                         float* __restrict__ yg) {
    int bc = blockIdx.x;                 // 0..5
    int o = threadIdx.x;                 // 0..127
    float s = 0;
#pragma unroll
    for (int seg = 0; seg < 32; ++seg) s += part[((long)bc * 32 + seg) * 128 + o];
    int b = bc / 3, c = bc % 3;
    yg[((long)(b * 128) + o) * 3 + c] = s * (1.0f / 4096.0f);
}

// ---------------- bias from global-mean half of Wg/Ug ----------------
__global__ __launch_bounds__(256) void bias_kernel(const float* __restrict__ Wg,
                                                   const float* __restrict__ Ug,
                                                   const float* __restrict__ yg,
                                                   float* __restrict__ biasP,
                                                   float* __restrict__ biasD) {
    int t = blockIdx.x * 256 + threadIdx.x;
    if (t >= 768) return;
    int c = t % 3; int o = (t / 3) % 128; int b = t / 384;
    float sp = 0.f, sd = 0.f;
    for (int i = 0; i < 128; ++i) {
        float y = yg[((long)b * 128 + i) * 3 + c];
        sp = fmaf(Wg[o * 256 + 128 + i], y, sp);
        sd = fmaf(Ug[o * 256 + 128 + i], y, sd);
    }
    biasP[t] = sp;
    biasD[t] = sd;
}

// ---------------- mean over N per (b, o, c) row of fp32 out1 ----------------
__global__ __launch_bounds__(256) void reduce_mean_kernel(const float* __restrict__ src, long bs,
                                                          float* __restrict__ dst, int N) {
    __shared__ float red[256];
    int row = blockIdx.x;          // (b*128+o)*3 + c
    int b = row / 384; int rr = row % 384;
    const float* p = src + (long)b * bs + (long)rr * N;
    float s = 0.f;
    for (int i = threadIdx.x; i < N; i += 256) s += p[i];
    red[threadIdx.x] = s;
    __syncthreads();
    for (int st = 128; st > 0; st >>= 1) {
        if (threadIdx.x < st) red[threadIdx.x] += red[threadIdx.x + st];
        __syncthreads();
    }
    if (threadIdx.x == 0) dst[row] = red[0] / (float)N;
}

extern "C" void kernel_launch(void* const* d_in, const int* in_sizes, int n_in,
                              void* d_out, int out_size, void* d_ws, size_t ws_size,
                              hipStream_t stream) {
    const float* x    = (const float*)d_in[0];
    const float* Win  = (const float*)d_in[1];
    const float* Uin  = (const float*)d_in[2];
    const float* Wl   = (const float*)d_in[3];
    const float* Ul   = (const float*)d_in[4];
    const float* Wg   = (const float*)d_in[5];
    const float* Ug   = (const float*)d_in[6];
    const float* Wout = (const float*)d_in[7];

    const int B = 2, N = 4096, H = 128;
    float* out0 = (float*)d_out;                 // (B,128,3) mean
    float* out1 = out0 + (long)B * H * 3;        // (B,128,3,N) fp32

    float* ws = (float*)d_ws;
    long off = 0;
    float4* pts4 = (float4*)ws;                  off += (long)B * N * 4;
    int* idx = (int*)(ws + off);                 off += (long)B * N * 16;
    const long ACT = (long)B * 3 * N * H;        // ushort count
    unsigned short* f0h = (unsigned short*)(ws + off);  off += ACT / 2;
    unsigned short* f0l = (unsigned short*)(ws + off);  off += ACT / 2;
    unsigned short* y1h = (unsigned short*)(ws + off);  off += ACT / 2;
    unsigned short* y1l = (unsigned short*)(ws + off);  off += ACT / 2;
    unsigned short* Aph = (unsigned short*)(ws + off);  off += 327680 / 2;
    unsigned short* Apl = (unsigned short*)(ws + off);  off += 327680 / 2;
    float* ygpart = ws + off;                    off += 6L * 32 * 128;
    float* yg    = ws + off;                     off += B * H * 3;
    float* biasP = ws + off;                     off += B * H * 3;
    float* biasD = ws + off;                     off += B * H * 3;
    // ~27.1 MB of workspace

    long bs128 = (long)H * 3 * N;

    prep_kernel<<<(B * N + 255) / 256, 256, 0, stream>>>(x, pts4, N, B);
    knn_kernel<<<B * (N / 16), 1024, 0, stream>>>(pts4, idx, N);
    edge_kernel<<<B * (N / 8), 256, 0, stream>>>(pts4, idx, Win, Uin, f0h, f0l, N);
    pack_kernel<<<1280, 256, 0, stream>>>(Wl, Ul, Wg, Ug, Wout, Aph, Apl);

    for (int l = 0; l < 4; ++l) {
        // y1 = LNA(Wl y2prev, Ul y2prev)
        gemm_kernel<0><<<256, 512, 0, stream>>>(
            Aph, Apl, (long)l * 32768, 0, f0h, f0l, nullptr, nullptr,
            y1h, y1l, nullptr, 0);
        // yg = mean_N(y1); bias = Wg[:,128:] @ yg (and Ug)
        reduce_yg1_kernel<<<192, 256, 0, stream>>>(y1h, y1l, ygpart);
        reduce_yg2_kernel<<<6, 128, 0, stream>>>(ygpart, yg);
        bias_kernel<<<3, 256, 0, stream>>>(Wg + (long)l * H * 256, Ug + (long)l * H * 256,
                                           yg, biasP, biasD);
        // y2 = LNA(Wg y1 + biasP, Ug y1 + biasD) -> f0 ; out1 (+)= Wout_l @ y2 (fused)
        gemm_kernel<1><<<256, 512, 0, stream>>>(
            Aph, Apl, (long)(4 + l) * 32768, 262144 + (long)l * 16384,
            y1h, y1l, biasP, biasD, f0h, f0l, out1, l > 0 ? 1 : 0);
    }
    reduce_mean_kernel<<<B * H * 3, 256, 0, stream>>>(out1, bs128, out0, N);
}